// Round 2
// baseline (112.906 us; speedup 1.0000x reference)
//
#include <hip/hip_runtime.h>
#include <math.h>

// LossLayer: dist[b,r] = ||W[b]-R[r]||2 ; pred = one_hot(argmax_r dist) ;
// loss = mean(1 + dist[b, argmax(label[b])] - dist[b, top2-excluding-y-at-top1])
//
// R2: BB=4 (grid 1024 -> 4 blocks/CU, 16 waves/CU = 50% occ; R1 had 256 blocks
// = 1 block/CU = 7% occ, pure latency-bound at VALUBusy 11%).
// Mapping: wave = one b-row, lane = relation r. W-tile LDS read is wave-uniform
// (broadcast, 16B); r-row reads stride 33 float4 -> 2-way bank alias (free).
#define NB 4096
#define NR 64
#define ND 512
#define BB 4           // b-rows per block = waves per block
#define NCHUNK 4       // D chunks of 128 floats (32 float4)
#define RSTRIDE 33     // float4 per LDS row: bank-step 4 -> 2-way (free)

__global__ __launch_bounds__(256, 4) void dist_topk_kernel(
    const float* __restrict__ w,
    const float* __restrict__ re,
    const float* __restrict__ label,
    float* __restrict__ out,
    float* __restrict__ ws)
{
    __shared__ float4 rl[NR * RSTRIDE];   // 33792 B
    __shared__ float4 wl[BB * RSTRIDE];   // 2112 B  -> total 35904 B

    const int tid = threadIdx.x;
    const int bq  = tid >> 6;       // wave id = local b row 0..3
    const int r   = tid & 63;       // lane = relation 0..63
    const int b0  = blockIdx.x * BB;
    const int b   = b0 + bq;

    const float4* wg  = (const float4*)w;    // [4096][128]
    const float4* rg4 = (const float4*)re;   // [64][128]

    float4 acc = {0.f, 0.f, 0.f, 0.f};

    // ---- prefetch chunk 0 into registers ----
    float4 pr[8];                    // re chunk: 64 rows x 32 cols = 2048 f4 / 256 thr
    float4 pw;                       // w  chunk: 4 rows x 32 cols = 128 f4 (tid<128)
    #pragma unroll
    for (int t = 0; t < 8; t++) {
        int idx = tid + t * 256; int row = idx >> 5; int col = idx & 31;
        pr[t] = rg4[row * 128 + col];
    }
    if (tid < 128) {
        int row = tid >> 5; int col = tid & 31;
        pw = wg[(size_t)(b0 + row) * 128 + col];
    }

    for (int c = 0; c < NCHUNK; c++) {
        // stage prefetched chunk into LDS
        #pragma unroll
        for (int t = 0; t < 8; t++) {
            int idx = tid + t * 256; int row = idx >> 5; int col = idx & 31;
            rl[row * RSTRIDE + col] = pr[t];
        }
        if (tid < 128) wl[(tid >> 5) * RSTRIDE + (tid & 31)] = pw;
        __syncthreads();

        if (c + 1 < NCHUNK) {       // prefetch next chunk while computing this one
            int dc4 = (c + 1) * 32;
            #pragma unroll
            for (int t = 0; t < 8; t++) {
                int idx = tid + t * 256; int row = idx >> 5; int col = idx & 31;
                pr[t] = rg4[row * 128 + dc4 + col];
            }
            if (tid < 128) {
                int row = tid >> 5; int col = tid & 31;
                pw = wg[(size_t)(b0 + row) * 128 + dc4 + col];
            }
        }

        const float4* wr = &wl[bq * RSTRIDE];   // wave-uniform -> LDS broadcast
        const float4* rr = &rl[r  * RSTRIDE];   // lane-varying rows, 2-way alias
        #pragma unroll
        for (int dd = 0; dd < 32; dd++) {
            float4 w4 = wr[dd];
            float4 r4 = rr[dd];
            float dx;
            dx = w4.x - r4.x; acc.x = fmaf(dx, dx, acc.x);
            dx = w4.y - r4.y; acc.y = fmaf(dx, dx, acc.y);
            dx = w4.z - r4.z; acc.z = fmaf(dx, dx, acc.z);
            dx = w4.w - r4.w; acc.w = fmaf(dx, dx, acc.w);
        }
        __syncthreads();
    }

    // 4 parallel chains -> low accumulation error
    float d = sqrtf((acc.x + acc.y) + (acc.z + acc.w));

    // ---- top-2 (value) + argmax (index, first-wins ties) across the wave ----
    float m1 = d; int i1 = r; float m2 = -3.0e38f;
    #pragma unroll
    for (int mask = 1; mask <= 32; mask <<= 1) {
        float om1 = __shfl_xor(m1, mask, 64);
        int   oi1 = __shfl_xor(i1, mask, 64);
        float om2 = __shfl_xor(m2, mask, 64);
        bool ob1 = (om1 > m1) || (om1 == m1 && oi1 < i1);
        float w1 = ob1 ? om1 : m1;  int wi1 = ob1 ? oi1 : i1;
        float l1 = ob1 ? m1 : om1;              // loser's top-1 (value only)
        float c2 = ob1 ? om2 : m2;              // winner's top-2 (value only)
        m1 = w1; i1 = wi1;
        m2 = (c2 > l1) ? c2 : l1;
    }

    // ---- y = argmax(label[b]) : one element per lane, coalesced ----
    float lv = label[(size_t)b * 64 + r]; int ly = r;
    #pragma unroll
    for (int mask = 1; mask <= 32; mask <<= 1) {
        float ov = __shfl_xor(lv, mask, 64);
        int   oy = __shfl_xor(ly, mask, 64);
        if (ov > lv || (ov == lv && oy < ly)) { lv = ov; ly = oy; }
    }
    int y = ly;

    float plus  = __shfl(d, y, 64);           // dist[b][y]
    float minus = (i1 == y) ? m2 : m1;        // top-2 value if top-1 == y
    if (r == 0) ws[b] = 1.0f + plus - minus;

    out[(size_t)b * 64 + r] = (i1 == r) ? 1.0f : 0.0f;   // pred one-hot
}

__global__ __launch_bounds__(256) void loss_reduce_kernel(
    const float* __restrict__ ws, float* __restrict__ out)
{
    int tid = threadIdx.x;
    float s = 0.0f;
    #pragma unroll
    for (int k = 0; k < 16; k++) s += ws[tid + 256 * k];
    #pragma unroll
    for (int m = 1; m < 64; m <<= 1) s += __shfl_xor(s, m, 64);
    __shared__ float part[4];
    if ((tid & 63) == 0) part[tid >> 6] = s;
    __syncthreads();
    if (tid == 0) out[(size_t)NB * NR] = (part[0] + part[1] + part[2] + part[3]) * (1.0f / NB);
}

extern "C" void kernel_launch(void* const* d_in, const int* in_sizes, int n_in,
                              void* d_out, int out_size, void* d_ws, size_t ws_size,
                              hipStream_t stream) {
    const float* w   = (const float*)d_in[0];   // [4096,512]
    const float* re  = (const float*)d_in[1];   // [64,512]
    const float* lab = (const float*)d_in[2];   // [4096,64]
    float* out = (float*)d_out;                 // pred [4096,64] ++ loss [1]
    float* ws  = (float*)d_ws;                  // per-b loss terms [4096]

    dist_topk_kernel<<<NB / BB, 256, 0, stream>>>(w, re, lab, out, ws);
    loss_reduce_kernel<<<1, 256, 0, stream>>>(ws, out);
}

// Round 3
// 106.480 us; speedup vs baseline: 1.0603x; 1.0603x over previous
//
#include <hip/hip_runtime.h>
#include <math.h>

// LossLayer: dist[b,r] = ||W[b]-R[r]||2 ; pred = one_hot(argmax_r dist) ;
// loss = mean(1 + dist[b,y] - dist[b, top2-excluding-y-at-top1]), y=argmax(label[b])
//
// R3: R2's __launch_bounds__(256,4) made the compiler cap VGPRs at 64 and spill
// the pr[8] prefetch array to scratch -> 118 MB HBM writes = the whole runtime.
// Fix: zero data VGPRs -- global_load_lds (16B) direct staging; re stored
// TRANSPOSED in LDS (rt[dd][r]) so compute reads are lane-consecutive 16B
// (conflict-free, no padding needed -- global_load_lds forbids padding).
// W tile staged once, read wave-uniform (LDS broadcast). 24 KB LDS ->
// 6 blocks/CU = 24 waves/CU. Loss reduction fused (atomic + completion counter).
#define NB 4096
#define NR 64
#define BB 4            // b-rows per block = waves per block; grid = 1024
#define NCH 8           // D chunks
#define CF4 16          // float4 dd-slices per chunk (64 floats)

#define AS1 __attribute__((address_space(1)))
#define AS3 __attribute__((address_space(3)))

__device__ __forceinline__ void async_copy16(void* lds, const void* g) {
    // LDS dest = wave-uniform base + lane*16 ; global addr is per-lane.
    __builtin_amdgcn_global_load_lds((const AS1 void*)g, (AS3 void*)lds, 16, 0, 0);
}

__global__ __launch_bounds__(256) void fused_loss_kernel(
    const float* __restrict__ w,
    const float* __restrict__ re,
    const float* __restrict__ label,
    float* __restrict__ out,
    float* __restrict__ ws)
{
    __shared__ float4 rt[CF4 * 64];   // [dd][r] transposed re chunk, 16 KB
    __shared__ float4 wl[BB * 128];   // [4][128] full W tile, 8 KB
    __shared__ float terms[BB];

    const int tid = threadIdx.x;
    const int wv  = tid >> 6;       // wave id = local b row 0..3 (wave-uniform)
    const int r   = tid & 63;       // lane = relation 0..63
    const int b0  = blockIdx.x * BB;
    const int b   = b0 + wv;

    const float4* w4  = (const float4*)w;    // [4096][128]
    const float4* re4 = (const float4*)re;   // [64][128]

    // ---- stage full W tile once: 512 f4, 2 issues/wave, contiguous both sides
    {
        int idx0 = wv * 64;
        async_copy16(&wl[idx0],       w4 + (size_t)b0 * 128 + idx0 + r);
        async_copy16(&wl[256 + idx0], w4 + (size_t)b0 * 128 + 256 + idx0 + r);
    }
    // ---- stage re chunk 0 transposed: slice dd covers all 64 r's (1 KB)
    #pragma unroll
    for (int q = 0; q < 4; q++) {
        int dd = q * 4 + wv;                         // wave-uniform slice id
        async_copy16(&rt[dd * 64], re4 + (size_t)r * 128 + dd);
    }

    float4 acc = {0.f, 0.f, 0.f, 0.f};

    for (int c = 0; c < NCH; c++) {
        __syncthreads();            // drains vmcnt(0): staged chunk (+W) complete

        const float4* wrow = &wl[wv * 128 + c * CF4];   // wave-uniform -> broadcast
        #pragma unroll
        for (int dd = 0; dd < CF4; dd++) {
            float4 a  = wrow[dd];          // LDS broadcast (conflict-free)
            float4 rr = rt[dd * 64 + r];   // lane-consecutive 16B (conflict-free)
            float dx;
            dx = a.x - rr.x; acc.x = fmaf(dx, dx, acc.x);
            dx = a.y - rr.y; acc.y = fmaf(dx, dx, acc.y);
            dx = a.z - rr.z; acc.z = fmaf(dx, dx, acc.z);
            dx = a.w - rr.w; acc.w = fmaf(dx, dx, acc.w);
        }

        if (c + 1 < NCH) {
            __syncthreads();        // all waves done reading rt before overwrite
            #pragma unroll
            for (int q = 0; q < 4; q++) {
                int dd = q * 4 + wv;
                async_copy16(&rt[dd * 64],
                             re4 + (size_t)r * 128 + (c + 1) * CF4 + dd);
            }
        }
    }

    // 4 parallel chains -> low accumulation error
    float d = sqrtf((acc.x + acc.y) + (acc.z + acc.w));

    // ---- top-2 (value) + argmax (index, first-wins ties) across the wave ----
    float m1 = d; int i1 = r; float m2 = -3.0e38f;
    #pragma unroll
    for (int mask = 1; mask <= 32; mask <<= 1) {
        float om1 = __shfl_xor(m1, mask, 64);
        int   oi1 = __shfl_xor(i1, mask, 64);
        float om2 = __shfl_xor(m2, mask, 64);
        bool ob1 = (om1 > m1) || (om1 == m1 && oi1 < i1);
        float w1 = ob1 ? om1 : m1;  int wi1 = ob1 ? oi1 : i1;
        float l1 = ob1 ? m1 : om1;              // loser's top-1 (value only)
        float c2 = ob1 ? om2 : m2;              // winner's top-2 (value only)
        m1 = w1; i1 = wi1;
        m2 = (c2 > l1) ? c2 : l1;
    }

    // ---- y = argmax(label[b]) : one element per lane, coalesced ----
    float lv = label[(size_t)b * 64 + r]; int ly = r;
    #pragma unroll
    for (int mask = 1; mask <= 32; mask <<= 1) {
        float ov = __shfl_xor(lv, mask, 64);
        int   oy = __shfl_xor(ly, mask, 64);
        if (ov > lv || (ov == lv && oy < ly)) { lv = ov; ly = oy; }
    }
    int y = ly;

    float plus  = __shfl(d, y, 64);           // dist[b][y]
    float minus = (i1 == y) ? m2 : m1;        // top-2 value if top-1 == y
    if (r == 0) terms[wv] = 1.0f + plus - minus;

    out[(size_t)b * 64 + r] = (i1 == r) ? 1.0f : 0.0f;   // pred one-hot

    // ---- fused loss reduction: block partial -> device atomic -> last block
    __syncthreads();
    if (tid == 0) {
        float t = ((terms[0] + terms[1]) + (terms[2] + terms[3])) * (1.0f / NB);
        atomicAdd(ws, t);                     // ws[0] = loss accumulator (zeroed)
        __threadfence();                      // order add before counter inc
        unsigned old = atomicAdd((unsigned*)(ws + 1), 1u);   // ws[1] = counter
        if (old == (unsigned)(gridDim.x - 1)) {
            float total = atomicAdd(ws, 0.0f);   // all 1024 adds visible
            out[(size_t)NB * NR] = total;
        }
    }
}

extern "C" void kernel_launch(void* const* d_in, const int* in_sizes, int n_in,
                              void* d_out, int out_size, void* d_ws, size_t ws_size,
                              hipStream_t stream) {
    const float* w   = (const float*)d_in[0];   // [4096,512]
    const float* re  = (const float*)d_in[1];   // [64,512]
    const float* lab = (const float*)d_in[2];   // [4096,64]
    float* out = (float*)d_out;                 // pred [4096,64] ++ loss [1]
    float* ws  = (float*)d_ws;                  // [0]=loss acc, [1]=done counter

    hipMemsetAsync(ws, 0, 8, stream);           // zero acc + counter (graph-safe)
    fused_loss_kernel<<<NB / BB, 256, 0, stream>>>(w, re, lab, out, ws);
}